// Round 10
// baseline (124.494 us; speedup 1.0000x reference)
//
#include <hip/hip_runtime.h>
#include <hip/hip_fp16.h>

#define B_    2
#define T_    400
#define NCH_  8
#define NBIN_ 512
#define NBAND_ 40
#define NPV_  64
#define NPREP_ 29
#define MAGIC_ 0x13579BDFu

using half8   = __attribute__((ext_vector_type(8))) _Float16;
using float4v = __attribute__((ext_vector_type(4))) float;

// pack two floats into fp16 pair dword (lo=x, hi=y), RNE
static __device__ inline unsigned pkhf(float x, float y) {
  __half2 h = __float22half2_rn(make_float2(x, y));
  return __builtin_bit_cast(unsigned, h);
}
static __device__ inline unsigned rot16(unsigned u) {
  return (u >> 16) | (u << 16);
}
// packed complex multiply a = v_i * conj(v_j); dwords are (lo=re, hi=im)
static __device__ inline unsigned cmulc(unsigned viu, unsigned vju) {
  __half2 Vi = __builtin_bit_cast(__half2, viu);
  __half2 Vj = __builtin_bit_cast(__half2, vju);
  __half2 P1 = __hmul2(Vi, __low2half2(Vj));
  __half2 Qi = __lowhigh2highlow(Vi);
  unsigned tn = __builtin_bit_cast(unsigned, __high2half2(Vj)) ^ 0x80000000u;
  __half2 a  = __hfma2(Qi, __builtin_bit_cast(__half2, tn), P1);
  return __builtin_bit_cast(unsigned, a);
}

// ws layout (bytes):
//   [0..159]              : dsinv[40] floats
//   [512..627]            : 29 completion flags (MAGIC_), one per prep block.
//                           ws is fully re-poisoned by the harness each
//                           iteration, so stale flags cannot leak across runs.
//   [1024, 1024+98304)    : band B-frags (fp16 pairs), s-major:
//                           F=(s*3+n)*64+lane, uint4; dword t = (bmr, bmi) at
//                           f = s*16 + (lane>>4)*4 + t, k = n*16 + (lane&15)
//   [197632, 197632+16384): epi B-frags (fp16): E=(nt*4+ks)*64+lane, uint4
//
// SINGLE kernel, grid 829 = 29 prep blocks + 800 frame blocks (saves one
// dispatch + one graph dependency edge vs the 3-kernel structure).
// Deadlock-proof: LDS 16 KiB + launch_bounds(256,4) (VGPR<=128; this exact
// structure compiled to 56 VGPR before) -> 4 blocks/CU -> 1024 resident
// slots >= 829 blocks, so prep blocks always run regardless of dispatch
// order (no G16 violation). Frame blocks touch ws only AFTER the flag wait;
// phase A (pure input reads) runs first and hides prep latency.
__global__ __launch_bounds__(256, 4) void pv_main(
    const float* __restrict__ bmr, const float* __restrict__ bmi,
    const float* __restrict__ c2pr, const float* __restrict__ c2pi,
    const float* __restrict__ br, const float* __restrict__ bi,
    float* __restrict__ ws, float* __restrict__ out)
{
  __shared__ __align__(16) unsigned smem[4096];
  const int tid = threadIdx.x;
  const int blk = blockIdx.x;
  unsigned* flags = (unsigned*)ws + 128;     // byte 512

  if (blk < NPREP_) {
    // ---------------- prep work (verbatim), then release flag ----------------
    if (blk == 0) {
      __shared__ float sds[256];
      int k = tid & 63, part = tid >> 6;
      float s = 0.f;
      if (k < NBAND_) {
        const float* col = bmr + k;
        #pragma unroll 16
        for (int f = part * 128; f < part * 128 + 128; f++) s += col[f * 40];
      }
      sds[tid] = s;
      __syncthreads();
      if (tid < NBAND_) {
        float t = sds[tid] + sds[tid + 64] + sds[tid + 128] + sds[tid + 192];
        ws[tid] = 1.0f / fmaxf(t, 1e-20f);
      }
    } else if (blk <= 24) {
      int F = (blk - 1) * 256 + tid;     // 0..6143
      int l = F & 63;
      int fid = F >> 6;                  // s*3 + n
      int s5 = fid / 3;
      int n = fid - s5 * 3;
      int k = n * 16 + (l & 15);
      int quad = l >> 4;
      unsigned dw[4];
      #pragma unroll
      for (int t2 = 0; t2 < 4; t2++) {
        float v0 = 0.f, v1 = 0.f;
        if (k < NBAND_) {
          int f = s5 * 16 + quad * 4 + t2;
          v0 = bmr[f * 40 + k]; v1 = bmi[f * 40 + k];
        }
        dw[t2] = pkhf(v0, v1);
      }
      ((uint4*)((char*)ws + 1024))[F] = make_uint4(dw[0], dw[1], dw[2], dw[3]);
    } else {
      int F2 = (blk - 25) * 256 + tid;   // 0..1023
      int lane = F2 & 63, E = F2 >> 6;
      int nt = E >> 2, ks = E & 3;
      int n = lane & 15, quad = lane >> 4;
      int p = nt * 16 + n;
      unsigned dw[4];
      #pragma unroll
      for (int t2 = 0; t2 < 4; t2++) {
        int c = ks * 16 + quad * 4 + t2;
        dw[t2] = pkhf(c2pr[p * 64 + c], -c2pi[p * 64 + c]);
      }
      ((uint4*)((char*)ws + 197632))[E * 64 + lane] = make_uint4(dw[0], dw[1], dw[2], dw[3]);
    }
    __syncthreads();                     // all block writes complete
    if (tid == 0) {
      __threadfence();                   // push to device-coherent point
      __hip_atomic_store(&flags[blk], MAGIC_, __ATOMIC_RELEASE,
                         __HIP_MEMORY_SCOPE_AGENT);
    }
    return;
  }

  // ---------------- frame block ----------------
  const int bt  = blk - NPREP_;        // 0..799 = b*T + t

  const int mt   = tid >> 6;       // wave id = M-tile
  const int lane = tid & 63;
  const int m16  = lane & 15;
  const int quad = lane >> 4;
  const int p    = mt * 16 + m16;
  const int ich  = p >> 3, jch = p & 7;
  const uint4* BF0 = (const uint4*)((const char*)ws + 1024);

  // ---- phase A: bins 2t,2t+1 per thread -> vsh (fp16 pairs, swizzled) ----
  // (no ws reads here; prep runs concurrently on other CUs)
  {
    const float* pr  = br + (size_t)bt * (NCH_ * NBIN_);
    const float* pim = bi + (size_t)bt * (NCH_ * NBIN_);
    unsigned* vsh = smem;
    const int f0 = 2 * tid;
    if (tid == 0 || tid == 255) {
      // original scalar path for edge bins (exact reference index mapping)
      #pragma unroll
      for (int bb = 0; bb < 2; bb++) {
        const int f = f0 + bb;
        const int fm = (f == 0) ? 0 : ((f == 511) ? 509 : f - 1);
        const int fp = (f == 0) ? 2 : ((f == 511) ? 511 : f + 1);
        float tr = 0.f;
        float t1[8], t2[8];
        #pragma unroll
        for (int c = 0; c < 8; c++) {
          const float* cr = pr + c * 512;
          const float* ci = pim + c * 512;
          float xr = cr[f],   xi = ci[f];
          float xrm = cr[fm], xim = ci[fm];
          float xrp = cr[fp], xip = ci[fp];
          tr = fmaf(xr, xr, tr); tr = fmaf(xi, xi, tr);
          float Gr = fmaf(xrm, xrp,  xim * xip);
          float Gi = fmaf(xrm, xip, -(xim * xrp));
          float am = fmaxf(fmaxf(fabsf(Gr), fabsf(Gi)), 1e-30f);
          float rc = __builtin_amdgcn_rcpf(am);
          float q1 = Gr * rc, q2 = Gi * rc;
          float n2 = fmaf(q1, q1, q2 * q2);
          float rn = __builtin_amdgcn_rsqf(n2);
          bool ok = n2 > 0.f;
          float ur = ok ? q1 * rn : 1.f;
          float ui = ok ? q2 * rn : 0.f;
          float mg = __builtin_amdgcn_sqrtf(fmaf(xr, xr, xi * xi));
          t1[c] = mg * ur; t2[c] = mg * ui;
        }
        float scv = __builtin_amdgcn_rsqf(fmaxf(tr, 1e-20f));
        const int fc = f >> 2, fl = f & 3;
        #pragma unroll
        for (int c = 0; c < 8; c++)
          vsh[c * 512 + ((fc ^ c) << 2) + fl] = pkhf(t1[c] * scv, t2[c] * scv);
      }
    } else {
      const int base = f0 - 1;           // window [f0-1 .. f0+2], in-bounds
      float tra = 0.f, trb = 0.f;
      float t1a[8], t2a[8], t1b[8], t2b[8];
      #pragma unroll
      for (int c = 0; c < 8; c++) {
        float4 wr, wi;
        __builtin_memcpy(&wr, pr + c * 512 + base, 16);
        __builtin_memcpy(&wi, pim + c * 512 + base, 16);
        // bin0 = f0: xr=wr.y,xi=wi.y  fm=(wr.x,wi.x)  fp=(wr.z,wi.z)
        {
          float xr = wr.y, xi = wi.y;
          float xrm = wr.x, xim = wi.x;
          float xrp = wr.z, xip = wi.z;
          tra = fmaf(xr, xr, tra); tra = fmaf(xi, xi, tra);
          float Gr = fmaf(xrm, xrp,  xim * xip);
          float Gi = fmaf(xrm, xip, -(xim * xrp));
          float am = fmaxf(fmaxf(fabsf(Gr), fabsf(Gi)), 1e-30f);
          float rc = __builtin_amdgcn_rcpf(am);
          float q1 = Gr * rc, q2 = Gi * rc;
          float n2 = fmaf(q1, q1, q2 * q2);
          float rn = __builtin_amdgcn_rsqf(n2);
          bool ok = n2 > 0.f;
          float ur = ok ? q1 * rn : 1.f;
          float ui = ok ? q2 * rn : 0.f;
          float mg = __builtin_amdgcn_sqrtf(fmaf(xr, xr, xi * xi));
          t1a[c] = mg * ur; t2a[c] = mg * ui;
        }
        // bin1 = f0+1: xr=wr.z,xi=wi.z  fm=(wr.y,wi.y)  fp=(wr.w,wi.w)
        {
          float xr = wr.z, xi = wi.z;
          float xrm = wr.y, xim = wi.y;
          float xrp = wr.w, xip = wi.w;
          trb = fmaf(xr, xr, trb); trb = fmaf(xi, xi, trb);
          float Gr = fmaf(xrm, xrp,  xim * xip);
          float Gi = fmaf(xrm, xip, -(xim * xrp));
          float am = fmaxf(fmaxf(fabsf(Gr), fabsf(Gi)), 1e-30f);
          float rc = __builtin_amdgcn_rcpf(am);
          float q1 = Gr * rc, q2 = Gi * rc;
          float n2 = fmaf(q1, q1, q2 * q2);
          float rn = __builtin_amdgcn_rsqf(n2);
          bool ok = n2 > 0.f;
          float ur = ok ? q1 * rn : 1.f;
          float ui = ok ? q2 * rn : 0.f;
          float mg = __builtin_amdgcn_sqrtf(fmaf(xr, xr, xi * xi));
          t1b[c] = mg * ur; t2b[c] = mg * ui;
        }
      }
      float scva = __builtin_amdgcn_rsqf(fmaxf(tra, 1e-20f));
      float scvb = __builtin_amdgcn_rsqf(fmaxf(trb, 1e-20f));
      const int fc = f0 >> 2, fl = f0 & 3;   // fl in {0,2}; same chunk for both bins
      #pragma unroll
      for (int c = 0; c < 8; c++) {
        unsigned d0 = pkhf(t1a[c] * scva, t2a[c] * scva);
        unsigned d1 = pkhf(t1b[c] * scvb, t2b[c] * scvb);
        *(uint2*)(vsh + c * 512 + ((fc ^ c) << 2) + fl) = make_uint2(d0, d1);
      }
    }
  }
  __syncthreads();               // vsh ready

  // ---- wait for prep flags before the first ws read (29 parallel spins) ----
  if (tid < NPREP_) {
    while (__hip_atomic_load(&flags[tid], __ATOMIC_ACQUIRE,
                             __HIP_MEMORY_SCOPE_AGENT) != MAGIC_)
      __builtin_amdgcn_s_sleep(2);
  }
  __syncthreads();               // ws (B-frags, epi, dsinv) published

  // ---- band GEMM: 32 K-steps; B-frags from L2 via 2-deep reg prefetch ----
  float4v acc[6];                // [0..2]=real cols, [3..5]=imag cols
  #pragma unroll
  for (int g = 0; g < 6; g++) acc[g] = (float4v){0.f, 0.f, 0.f, 0.f};

  const uint4* Bg = BF0 + lane;
  uint4 pa0 = Bg[0],   pa1 = Bg[64],  pa2 = Bg[128];   // step s
  uint4 pb0 = Bg[192], pb1 = Bg[256], pb2 = Bg[320];   // step s+1
  #pragma unroll 4
  for (int s = 0; s < 32; s++) {
    uint4 cb0 = pa0, cb1 = pa1, cb2 = pa2;
    pa0 = pb0; pa1 = pb1; pa2 = pb2;
    {
      const uint4* nx = Bg + (size_t)(((s + 2) & 31) * 192);
      pb0 = nx[0]; pb1 = nx[64]; pb2 = nx[128];
    }
    const int sc = s * 4 + quad;           // chunk index pre-swizzle
    half8 b0 = __builtin_bit_cast(half8, cb0);
    half8 b1 = __builtin_bit_cast(half8, cb1);
    half8 b2 = __builtin_bit_cast(half8, cb2);
    const uint4* vb = (const uint4*)smem;
    uint4 av = vb[ich * 128 + (sc ^ ich)];
    uint4 bv = vb[jch * 128 + (sc ^ jch)];
    unsigned a0 = cmulc(av.x, bv.x);
    unsigned a1 = cmulc(av.y, bv.y);
    unsigned a2 = cmulc(av.z, bv.z);
    unsigned a3 = cmulc(av.w, bv.w);
    uint4 au1 = make_uint4(a0 ^ 0x80000000u, a1 ^ 0x80000000u,
                           a2 ^ 0x80000000u, a3 ^ 0x80000000u); // (ar, -ai)
    uint4 au2 = make_uint4(rot16(a0), rot16(a1),
                           rot16(a2), rot16(a3));               // (ai, ar)
    half8 af1 = __builtin_bit_cast(half8, au1);
    half8 af2 = __builtin_bit_cast(half8, au2);
    acc[0] = __builtin_amdgcn_mfma_f32_16x16x32_f16(af1, b0, acc[0], 0, 0, 0);
    acc[3] = __builtin_amdgcn_mfma_f32_16x16x32_f16(af2, b0, acc[3], 0, 0, 0);
    acc[1] = __builtin_amdgcn_mfma_f32_16x16x32_f16(af1, b1, acc[1], 0, 0, 0);
    acc[4] = __builtin_amdgcn_mfma_f32_16x16x32_f16(af2, b1, acc[4], 0, 0, 0);
    acc[2] = __builtin_amdgcn_mfma_f32_16x16x32_f16(af1, b2, acc[2], 0, 0, 0);
    acc[5] = __builtin_amdgcn_mfma_f32_16x16x32_f16(af2, b2, acc[5], 0, 0, 0);
  }
  __syncthreads();               // all waves done reading vsh before overlay

  // ---- epilogue GEMM: pv[k][p] = Re(sum_c c2p[p][c]*bc[k][c]) ----
  const uint4* EF = ((const uint4*)((const char*)ws + 197632)) + (mt * 4) * 64 + lane;
  uint4 eb[4];
  #pragma unroll
  for (int ks = 0; ks < 4; ks++) eb[ks] = EF[ks * 64];

  {
    unsigned* bcsh = smem;             // [48][68] fp16-pair, overlays vsh
    #pragma unroll
    for (int n = 0; n < 3; n++) {
      uint4 w4 = make_uint4(pkhf(acc[n][0], acc[n+3][0]),
                            pkhf(acc[n][1], acc[n+3][1]),
                            pkhf(acc[n][2], acc[n+3][2]),
                            pkhf(acc[n][3], acc[n+3][3]));
      *(uint4*)(bcsh + (n * 16 + m16) * 68 + mt * 16 + quad * 4) = w4;
    }
  }
  __syncthreads();

  const float4* wsd = (const float4*)ws;   // dsinv[40]
  {
    const unsigned* bcsh = smem;
    float4v eacc[3];
    #pragma unroll
    for (int kt = 0; kt < 3; kt++) eacc[kt] = (float4v){0.f, 0.f, 0.f, 0.f};
    #pragma unroll
    for (int ks = 0; ks < 4; ks++) {
      half8 bfr = __builtin_bit_cast(half8, eb[ks]);
      #pragma unroll
      for (int kt = 0; kt < 3; kt++) {
        uint4 a4 = *(const uint4*)(bcsh + (kt * 16 + m16) * 68 + ks * 16 + quad * 4);
        half8 afr = __builtin_bit_cast(half8, a4);
        eacc[kt] = __builtin_amdgcn_mfma_f32_16x16x32_f16(afr, bfr, eacc[kt], 0, 0, 0);
      }
    }
    float* op = out + (size_t)bt * (NBAND_ * NPV_);
    #pragma unroll
    for (int kt = 0; kt < 3; kt++) {
      float4 dv = wsd[kt * 4 + quad];
      float dva[4] = {dv.x, dv.y, dv.z, dv.w};
      #pragma unroll
      for (int r = 0; r < 4; r++) {
        int k = kt * 16 + quad * 4 + r;
        if (k < NBAND_)
          op[k * 64 + mt * 16 + m16] = eacc[kt][r] * dva[r];
      }
    }
  }
}

// ---------------- IIR: chunked scan, chunk=10, 320 blocks x 640 thr ----------------
// 3200 waves (2.5x R10) for latency hiding; combine = 39-deep predicated fma fold.
__global__ __launch_bounds__(640) void pv_iir4(float* __restrict__ z,
                                               const float* __restrict__ tau)
{
  __shared__ float gsh[40][16];
  const int pg = blockIdx.x & 3;
  const int bk = blockIdx.x >> 2;            // 0..79 = b*40+k
  const int k = bk % NBAND_;
  const int b = bk / NBAND_;
  const float a  = tau[k];
  const float om = 1.0f - a;
  const int c  = threadIdx.x >> 4;           // chunk 0..39
  const int pl = threadIdx.x & 15;
  const int p  = pg * 16 + pl;
  const size_t stride = (size_t)NBAND_ * 64;
  size_t idx0 = (size_t)b * (T_ * NBAND_ * 64) + (size_t)(c * 10) * stride + k * 64 + p;

  float y[10];
  float accv = 0.f;
  #pragma unroll
  for (int i = 0; i < 10; i++) {
    float v = z[idx0 + (size_t)i * stride];
    accv = fmaf(a, accv, om * v);
    y[i] = accv;
  }
  gsh[c][pl] = accv;
  __syncthreads();
  float a2 = a * a, a4 = a2 * a2, a8 = a4 * a4;
  float A = a8 * a2;                         // a^10
  float H = 0.f;
  #pragma unroll
  for (int d = 0; d < 39; d++) {
    float g = gsh[d][pl];
    H = (d < c) ? fmaf(A, H, g) : H;
  }
  float wp = a;
  #pragma unroll
  for (int i = 0; i < 10; i++) {
    z[idx0 + (size_t)i * stride] = fmaf(wp, H, y[i]);
    wp *= a;
  }
}

extern "C" void kernel_launch(void* const* d_in, const int* in_sizes, int n_in,
                              void* d_out, int out_size, void* d_ws, size_t ws_size,
                              hipStream_t stream)
{
  const float* br   = (const float*)d_in[0];
  const float* bi   = (const float*)d_in[1];
  const float* bmr  = (const float*)d_in[2];
  const float* bmi  = (const float*)d_in[3];
  const float* c2pr = (const float*)d_in[4];
  const float* c2pi = (const float*)d_in[5];
  const float* tau  = (const float*)d_in[6];
  float* out = (float*)d_out;
  float* ws  = (float*)d_ws;

  hipLaunchKernelGGL(pv_main, dim3(NPREP_ + B_ * T_), dim3(256), 0, stream,
                     bmr, bmi, c2pr, c2pi, br, bi, ws, out);
  hipLaunchKernelGGL(pv_iir4, dim3(B_ * NBAND_ * 4), dim3(640), 0, stream,
                     out, tau);
}

// Round 11
// 108.111 us; speedup vs baseline: 1.1515x; 1.1515x over previous
//
#include <hip/hip_runtime.h>
#include <hip/hip_fp16.h>

#define B_    2
#define T_    400
#define NCH_  8
#define NBIN_ 512
#define NBAND_ 40
#define NPV_  64

using half8   = __attribute__((ext_vector_type(8))) _Float16;
using float4v = __attribute__((ext_vector_type(4))) float;

// pack two floats into fp16 pair dword (lo=x, hi=y), RNE
static __device__ inline unsigned pkhf(float x, float y) {
  __half2 h = __float22half2_rn(make_float2(x, y));
  return __builtin_bit_cast(unsigned, h);
}
static __device__ inline unsigned rot16(unsigned u) {
  return (u >> 16) | (u << 16);
}
// packed complex multiply a = v_i * conj(v_j); dwords are (lo=re, hi=im)
static __device__ inline unsigned cmulc(unsigned viu, unsigned vju) {
  __half2 Vi = __builtin_bit_cast(__half2, viu);
  __half2 Vj = __builtin_bit_cast(__half2, vju);
  __half2 P1 = __hmul2(Vi, __low2half2(Vj));
  __half2 Qi = __lowhigh2highlow(Vi);
  unsigned tn = __builtin_bit_cast(unsigned, __high2half2(Vj)) ^ 0x80000000u;
  __half2 a  = __hfma2(Qi, __builtin_bit_cast(__half2, tn), P1);
  return __builtin_bit_cast(unsigned, a);
}

// ws layout (bytes):
//   [0..159]              : dsinv[40] floats
//   [1024, 1024+98304)    : band B-frags (fp16 pairs), s-major, stored once:
//                           F=(s*3+n)*64+lane, uint4; dword t = (bmr, bmi) at
//                           f = s*16 + (lane>>4)*4 + t, k = n*16 + (lane&15)
//   [197632, 197632+16384): epi B-frags (fp16): E=(nt*4+ks)*64+lane, uint4
__global__ __launch_bounds__(256) void pv_prep(
    const float* __restrict__ bmr, const float* __restrict__ bmi,
    const float* __restrict__ c2pr, const float* __restrict__ c2pi,
    float* __restrict__ ws)
{
  const int tid = threadIdx.x;
  const int blk = blockIdx.x;
  if (blk == 0) {
    __shared__ float sds[256];
    int k = tid & 63, part = tid >> 6;
    float s = 0.f;
    if (k < NBAND_) {
      const float* col = bmr + k;
      #pragma unroll 16
      for (int f = part * 128; f < part * 128 + 128; f++) s += col[f * 40];
    }
    sds[tid] = s;
    __syncthreads();
    if (tid < NBAND_) {
      float t = sds[tid] + sds[tid + 64] + sds[tid + 128] + sds[tid + 192];
      ws[tid] = 1.0f / fmaxf(t, 1e-20f);
    }
  } else if (blk <= 24) {
    int F = (blk - 1) * 256 + tid;     // 0..6143
    int l = F & 63;
    int fid = F >> 6;                  // s*3 + n
    int s5 = fid / 3;
    int n = fid - s5 * 3;
    int k = n * 16 + (l & 15);
    int quad = l >> 4;
    unsigned dw[4];
    #pragma unroll
    for (int t2 = 0; t2 < 4; t2++) {
      float v0 = 0.f, v1 = 0.f;
      if (k < NBAND_) {
        int f = s5 * 16 + quad * 4 + t2;
        v0 = bmr[f * 40 + k]; v1 = bmi[f * 40 + k];
      }
      dw[t2] = pkhf(v0, v1);
    }
    ((uint4*)((char*)ws + 1024))[F] = make_uint4(dw[0], dw[1], dw[2], dw[3]);
  } else {
    int F2 = (blk - 25) * 256 + tid;   // 0..1023
    int lane = F2 & 63, E = F2 >> 6;
    int nt = E >> 2, ks = E & 3;
    int n = lane & 15, quad = lane >> 4;
    int p = nt * 16 + n;
    unsigned dw[4];
    #pragma unroll
    for (int t2 = 0; t2 < 4; t2++) {
      int c = ks * 16 + quad * 4 + t2;
      dw[t2] = pkhf(c2pr[p * 64 + c], -c2pi[p * 64 + c]);
    }
    ((uint4*)((char*)ws + 197632))[E * 64 + lane] = make_uint4(dw[0], dw[1], dw[2], dw[3]);
  }
}

// ONE frame per block, 800 blocks. Phase A vectorized: thread t owns ADJACENT
// bins f=2t,2t+1; one unaligned dwordx4 per (channel, re/im) covers all six
// operands of both bins (window [2t-1 .. 2t+2]). Edge threads t=0,255 take
// the original scalar path. K-loop: 2-deep register prefetch of B-frags
// (L2-hot). LDS = vsh 16,384 B. [verified 112.3us structure — unchanged]
//   vsh uint[8][512] @0  (XOR-chunk swizzle (c,f): c*512+(((f>>2)^c)<<2)+(f&3))
//   epilogue: bcsh uint[48][68] overlays vsh
__global__ __launch_bounds__(256, 3) void pv_main(
    const float* __restrict__ br, const float* __restrict__ bi,
    const float* __restrict__ ws, float* __restrict__ out)
{
  __shared__ __align__(16) unsigned smem[4096];

  const int bt  = blockIdx.x;          // 0..799 = b*T + t
  const int tid = threadIdx.x;

  const int mt   = tid >> 6;       // wave id = M-tile
  const int lane = tid & 63;
  const int m16  = lane & 15;
  const int quad = lane >> 4;
  const int p    = mt * 16 + m16;
  const int ich  = p >> 3, jch = p & 7;
  const uint4* BF0 = (const uint4*)((const char*)ws + 1024);

  // ---- phase A: bins 2t,2t+1 per thread -> vsh (fp16 pairs, swizzled) ----
  {
    const float* pr  = br + (size_t)bt * (NCH_ * NBIN_);
    const float* pim = bi + (size_t)bt * (NCH_ * NBIN_);
    unsigned* vsh = smem;
    const int f0 = 2 * tid;
    if (tid == 0 || tid == 255) {
      // original scalar path for edge bins (exact reference index mapping)
      #pragma unroll
      for (int bb = 0; bb < 2; bb++) {
        const int f = f0 + bb;
        const int fm = (f == 0) ? 0 : ((f == 511) ? 509 : f - 1);
        const int fp = (f == 0) ? 2 : ((f == 511) ? 511 : f + 1);
        float tr = 0.f;
        float t1[8], t2[8];
        #pragma unroll
        for (int c = 0; c < 8; c++) {
          const float* cr = pr + c * 512;
          const float* ci = pim + c * 512;
          float xr = cr[f],   xi = ci[f];
          float xrm = cr[fm], xim = ci[fm];
          float xrp = cr[fp], xip = ci[fp];
          tr = fmaf(xr, xr, tr); tr = fmaf(xi, xi, tr);
          float Gr = fmaf(xrm, xrp,  xim * xip);
          float Gi = fmaf(xrm, xip, -(xim * xrp));
          float am = fmaxf(fmaxf(fabsf(Gr), fabsf(Gi)), 1e-30f);
          float rc = __builtin_amdgcn_rcpf(am);
          float q1 = Gr * rc, q2 = Gi * rc;
          float n2 = fmaf(q1, q1, q2 * q2);
          float rn = __builtin_amdgcn_rsqf(n2);
          bool ok = n2 > 0.f;
          float ur = ok ? q1 * rn : 1.f;
          float ui = ok ? q2 * rn : 0.f;
          float mg = __builtin_amdgcn_sqrtf(fmaf(xr, xr, xi * xi));
          t1[c] = mg * ur; t2[c] = mg * ui;
        }
        float scv = __builtin_amdgcn_rsqf(fmaxf(tr, 1e-20f));
        const int fc = f >> 2, fl = f & 3;
        #pragma unroll
        for (int c = 0; c < 8; c++)
          vsh[c * 512 + ((fc ^ c) << 2) + fl] = pkhf(t1[c] * scv, t2[c] * scv);
      }
    } else {
      const int base = f0 - 1;           // window [f0-1 .. f0+2], in-bounds
      float tra = 0.f, trb = 0.f;
      float t1a[8], t2a[8], t1b[8], t2b[8];
      #pragma unroll
      for (int c = 0; c < 8; c++) {
        float4 wr, wi;
        __builtin_memcpy(&wr, pr + c * 512 + base, 16);
        __builtin_memcpy(&wi, pim + c * 512 + base, 16);
        // bin0 = f0: xr=wr.y,xi=wi.y  fm=(wr.x,wi.x)  fp=(wr.z,wi.z)
        {
          float xr = wr.y, xi = wi.y;
          float xrm = wr.x, xim = wi.x;
          float xrp = wr.z, xip = wi.z;
          tra = fmaf(xr, xr, tra); tra = fmaf(xi, xi, tra);
          float Gr = fmaf(xrm, xrp,  xim * xip);
          float Gi = fmaf(xrm, xip, -(xim * xrp));
          float am = fmaxf(fmaxf(fabsf(Gr), fabsf(Gi)), 1e-30f);
          float rc = __builtin_amdgcn_rcpf(am);
          float q1 = Gr * rc, q2 = Gi * rc;
          float n2 = fmaf(q1, q1, q2 * q2);
          float rn = __builtin_amdgcn_rsqf(n2);
          bool ok = n2 > 0.f;
          float ur = ok ? q1 * rn : 1.f;
          float ui = ok ? q2 * rn : 0.f;
          float mg = __builtin_amdgcn_sqrtf(fmaf(xr, xr, xi * xi));
          t1a[c] = mg * ur; t2a[c] = mg * ui;
        }
        // bin1 = f0+1: xr=wr.z,xi=wi.z  fm=(wr.y,wi.y)  fp=(wr.w,wi.w)
        {
          float xr = wr.z, xi = wi.z;
          float xrm = wr.y, xim = wi.y;
          float xrp = wr.w, xip = wi.w;
          trb = fmaf(xr, xr, trb); trb = fmaf(xi, xi, trb);
          float Gr = fmaf(xrm, xrp,  xim * xip);
          float Gi = fmaf(xrm, xip, -(xim * xrp));
          float am = fmaxf(fmaxf(fabsf(Gr), fabsf(Gi)), 1e-30f);
          float rc = __builtin_amdgcn_rcpf(am);
          float q1 = Gr * rc, q2 = Gi * rc;
          float n2 = fmaf(q1, q1, q2 * q2);
          float rn = __builtin_amdgcn_rsqf(n2);
          bool ok = n2 > 0.f;
          float ur = ok ? q1 * rn : 1.f;
          float ui = ok ? q2 * rn : 0.f;
          float mg = __builtin_amdgcn_sqrtf(fmaf(xr, xr, xi * xi));
          t1b[c] = mg * ur; t2b[c] = mg * ui;
        }
      }
      float scva = __builtin_amdgcn_rsqf(fmaxf(tra, 1e-20f));
      float scvb = __builtin_amdgcn_rsqf(fmaxf(trb, 1e-20f));
      const int fc = f0 >> 2, fl = f0 & 3;   // fl in {0,2}; same chunk for both bins
      #pragma unroll
      for (int c = 0; c < 8; c++) {
        unsigned d0 = pkhf(t1a[c] * scva, t2a[c] * scva);
        unsigned d1 = pkhf(t1b[c] * scvb, t2b[c] * scvb);
        *(uint2*)(vsh + c * 512 + ((fc ^ c) << 2) + fl) = make_uint2(d0, d1);
      }
    }
  }
  __syncthreads();               // vsh ready; K-loop below is barrier-free

  // ---- band GEMM: 32 K-steps; B-frags from L2 via 2-deep reg prefetch ----
  float4v acc[6];                // [0..2]=real cols, [3..5]=imag cols
  #pragma unroll
  for (int g = 0; g < 6; g++) acc[g] = (float4v){0.f, 0.f, 0.f, 0.f};

  const uint4* Bg = BF0 + lane;
  uint4 pa0 = Bg[0],   pa1 = Bg[64],  pa2 = Bg[128];   // step s
  uint4 pb0 = Bg[192], pb1 = Bg[256], pb2 = Bg[320];   // step s+1
  #pragma unroll 4
  for (int s = 0; s < 32; s++) {
    uint4 cb0 = pa0, cb1 = pa1, cb2 = pa2;
    pa0 = pb0; pa1 = pb1; pa2 = pb2;
    {
      const uint4* nx = Bg + (size_t)(((s + 2) & 31) * 192);
      pb0 = nx[0]; pb1 = nx[64]; pb2 = nx[128];
    }
    const int sc = s * 4 + quad;           // chunk index pre-swizzle
    half8 b0 = __builtin_bit_cast(half8, cb0);
    half8 b1 = __builtin_bit_cast(half8, cb1);
    half8 b2 = __builtin_bit_cast(half8, cb2);
    const uint4* vb = (const uint4*)smem;
    uint4 av = vb[ich * 128 + (sc ^ ich)];
    uint4 bv = vb[jch * 128 + (sc ^ jch)];
    unsigned a0 = cmulc(av.x, bv.x);
    unsigned a1 = cmulc(av.y, bv.y);
    unsigned a2 = cmulc(av.z, bv.z);
    unsigned a3 = cmulc(av.w, bv.w);
    uint4 au1 = make_uint4(a0 ^ 0x80000000u, a1 ^ 0x80000000u,
                           a2 ^ 0x80000000u, a3 ^ 0x80000000u); // (ar, -ai)
    uint4 au2 = make_uint4(rot16(a0), rot16(a1),
                           rot16(a2), rot16(a3));               // (ai, ar)
    half8 af1 = __builtin_bit_cast(half8, au1);
    half8 af2 = __builtin_bit_cast(half8, au2);
    acc[0] = __builtin_amdgcn_mfma_f32_16x16x32_f16(af1, b0, acc[0], 0, 0, 0);
    acc[3] = __builtin_amdgcn_mfma_f32_16x16x32_f16(af2, b0, acc[3], 0, 0, 0);
    acc[1] = __builtin_amdgcn_mfma_f32_16x16x32_f16(af1, b1, acc[1], 0, 0, 0);
    acc[4] = __builtin_amdgcn_mfma_f32_16x16x32_f16(af2, b1, acc[4], 0, 0, 0);
    acc[2] = __builtin_amdgcn_mfma_f32_16x16x32_f16(af1, b2, acc[2], 0, 0, 0);
    acc[5] = __builtin_amdgcn_mfma_f32_16x16x32_f16(af2, b2, acc[5], 0, 0, 0);
  }
  __syncthreads();               // all waves done reading vsh before overlay

  // ---- epilogue GEMM: pv[k][p] = Re(sum_c c2p[p][c]*bc[k][c]) ----
  const uint4* EF = ((const uint4*)((const char*)ws + 197632)) + (mt * 4) * 64 + lane;
  uint4 eb[4];
  #pragma unroll
  for (int ks = 0; ks < 4; ks++) eb[ks] = EF[ks * 64];

  {
    unsigned* bcsh = smem;             // [48][68] fp16-pair, overlays vsh
    #pragma unroll
    for (int n = 0; n < 3; n++) {
      uint4 w4 = make_uint4(pkhf(acc[n][0], acc[n+3][0]),
                            pkhf(acc[n][1], acc[n+3][1]),
                            pkhf(acc[n][2], acc[n+3][2]),
                            pkhf(acc[n][3], acc[n+3][3]));
      *(uint4*)(bcsh + (n * 16 + m16) * 68 + mt * 16 + quad * 4) = w4;
    }
  }
  __syncthreads();

  const float4* wsd = (const float4*)ws;   // dsinv[40]
  {
    const unsigned* bcsh = smem;
    float4v eacc[3];
    #pragma unroll
    for (int kt = 0; kt < 3; kt++) eacc[kt] = (float4v){0.f, 0.f, 0.f, 0.f};
    #pragma unroll
    for (int ks = 0; ks < 4; ks++) {
      half8 bfr = __builtin_bit_cast(half8, eb[ks]);
      #pragma unroll
      for (int kt = 0; kt < 3; kt++) {
        uint4 a4 = *(const uint4*)(bcsh + (kt * 16 + m16) * 68 + ks * 16 + quad * 4);
        half8 afr = __builtin_bit_cast(half8, a4);
        eacc[kt] = __builtin_amdgcn_mfma_f32_16x16x32_f16(afr, bfr, eacc[kt], 0, 0, 0);
      }
    }
    float* op = out + (size_t)bt * (NBAND_ * NPV_);
    #pragma unroll
    for (int kt = 0; kt < 3; kt++) {
      float4 dv = wsd[kt * 4 + quad];
      float dva[4] = {dv.x, dv.y, dv.z, dv.w};
      #pragma unroll
      for (int r = 0; r < 4; r++) {
        int k = kt * 16 + quad * 4 + r;
        if (k < NBAND_)
          op[k * 64 + mt * 16 + m16] = eacc[kt][r] * dva[r];
      }
    }
  }
}

// ---------------- IIR: chunked scan, chunk=25, 80 blocks x 1024 thr ----------------
// block = (b,k); thread = (chunk c in [0,16), p in [0,64)). Each wave is all
// 64 p of ONE chunk -> every load/store is a single fully-coalesced 256-B
// transaction (old layout: 4 scattered 64-B lines per instr). 25 independent
// loads pipeline per thread; combine fold 15-deep (was 39); zero block tail
// (80 blocks, 1/CU). Same verified scan math with A = a^25.
__global__ __launch_bounds__(1024) void pv_iir4(float* __restrict__ z,
                                                const float* __restrict__ tau)
{
  __shared__ float gsh[16][64];
  const int bk = blockIdx.x;                 // 0..79 = b*40+k
  const int k = bk % NBAND_;
  const int b = bk / NBAND_;
  const float a  = tau[k];
  const float om = 1.0f - a;
  const int c = threadIdx.x >> 6;            // chunk 0..15
  const int p = threadIdx.x & 63;
  const size_t stride = (size_t)NBAND_ * 64;
  size_t idx0 = (size_t)b * (T_ * NBAND_ * 64) + (size_t)(c * 25) * stride + k * 64 + p;

  float y[25];
  float accv = 0.f;
  #pragma unroll
  for (int i = 0; i < 25; i++) {
    float v = z[idx0 + (size_t)i * stride];
    accv = fmaf(a, accv, om * v);
    y[i] = accv;
  }
  gsh[c][p] = accv;
  __syncthreads();
  float a2 = a * a, a4 = a2 * a2, a8 = a4 * a4, a16 = a8 * a8;
  float A = a16 * a8 * a;                    // a^25
  float H = 0.f;
  #pragma unroll
  for (int d = 0; d < 15; d++) {
    float g = gsh[d][p];
    H = (d < c) ? fmaf(A, H, g) : H;
  }
  float wp = a;
  #pragma unroll
  for (int i = 0; i < 25; i++) {
    z[idx0 + (size_t)i * stride] = fmaf(wp, H, y[i]);
    wp *= a;
  }
}

extern "C" void kernel_launch(void* const* d_in, const int* in_sizes, int n_in,
                              void* d_out, int out_size, void* d_ws, size_t ws_size,
                              hipStream_t stream)
{
  const float* br   = (const float*)d_in[0];
  const float* bi   = (const float*)d_in[1];
  const float* bmr  = (const float*)d_in[2];
  const float* bmi  = (const float*)d_in[3];
  const float* c2pr = (const float*)d_in[4];
  const float* c2pi = (const float*)d_in[5];
  const float* tau  = (const float*)d_in[6];
  float* out = (float*)d_out;
  float* ws  = (float*)d_ws;

  hipLaunchKernelGGL(pv_prep, dim3(29), dim3(256), 0, stream,
                     bmr, bmi, c2pr, c2pi, ws);
  hipLaunchKernelGGL(pv_main, dim3(B_ * T_), dim3(256), 0, stream,
                     br, bi, ws, out);
  hipLaunchKernelGGL(pv_iir4, dim3(B_ * NBAND_), dim3(1024), 0, stream,
                     out, tau);
}

// Round 12
// 107.866 us; speedup vs baseline: 1.1542x; 1.0023x over previous
//
#include <hip/hip_runtime.h>
#include <hip/hip_fp16.h>

#define B_    2
#define T_    400
#define NCH_  8
#define NBIN_ 512
#define NBAND_ 40
#define NPV_  64

using half8   = __attribute__((ext_vector_type(8))) _Float16;
using float4v = __attribute__((ext_vector_type(4))) float;

// pack two floats into fp16 pair dword (lo=x, hi=y), RNE
static __device__ inline unsigned pkhf(float x, float y) {
  __half2 h = __float22half2_rn(make_float2(x, y));
  return __builtin_bit_cast(unsigned, h);
}
static __device__ inline unsigned rot16(unsigned u) {
  return (u >> 16) | (u << 16);
}
// packed complex multiply a = v_i * conj(v_j); dwords are (lo=re, hi=im)
static __device__ inline unsigned cmulc(unsigned viu, unsigned vju) {
  __half2 Vi = __builtin_bit_cast(__half2, viu);
  __half2 Vj = __builtin_bit_cast(__half2, vju);
  __half2 P1 = __hmul2(Vi, __low2half2(Vj));
  __half2 Qi = __lowhigh2highlow(Vi);
  unsigned tn = __builtin_bit_cast(unsigned, __high2half2(Vj)) ^ 0x80000000u;
  __half2 a  = __hfma2(Qi, __builtin_bit_cast(__half2, tn), P1);
  return __builtin_bit_cast(unsigned, a);
}

// ws layout (bytes):
//   [0..159]              : dsinv[40] floats
//   [1024, 1024+98304)    : band B-frags (fp16 pairs), s-major, stored once:
//                           F=(s*3+n)*64+lane, uint4; dword t = (bmr, bmi) at
//                           f = s*16 + (lane>>4)*4 + t, k = n*16 + (lane&15)
//   [197632, 197632+16384): epi B-frags (fp16): E=(nt*4+ks)*64+lane, uint4
__global__ __launch_bounds__(256) void pv_prep(
    const float* __restrict__ bmr, const float* __restrict__ bmi,
    const float* __restrict__ c2pr, const float* __restrict__ c2pi,
    float* __restrict__ ws)
{
  const int tid = threadIdx.x;
  const int blk = blockIdx.x;
  if (blk == 0) {
    __shared__ float sds[256];
    int k = tid & 63, part = tid >> 6;
    float s = 0.f;
    if (k < NBAND_) {
      const float* col = bmr + k;
      #pragma unroll 16
      for (int f = part * 128; f < part * 128 + 128; f++) s += col[f * 40];
    }
    sds[tid] = s;
    __syncthreads();
    if (tid < NBAND_) {
      float t = sds[tid] + sds[tid + 64] + sds[tid + 128] + sds[tid + 192];
      ws[tid] = 1.0f / fmaxf(t, 1e-20f);
    }
  } else if (blk <= 24) {
    int F = (blk - 1) * 256 + tid;     // 0..6143
    int l = F & 63;
    int fid = F >> 6;                  // s*3 + n
    int s5 = fid / 3;
    int n = fid - s5 * 3;
    int k = n * 16 + (l & 15);
    int quad = l >> 4;
    unsigned dw[4];
    #pragma unroll
    for (int t2 = 0; t2 < 4; t2++) {
      float v0 = 0.f, v1 = 0.f;
      if (k < NBAND_) {
        int f = s5 * 16 + quad * 4 + t2;
        v0 = bmr[f * 40 + k]; v1 = bmi[f * 40 + k];
      }
      dw[t2] = pkhf(v0, v1);
    }
    ((uint4*)((char*)ws + 1024))[F] = make_uint4(dw[0], dw[1], dw[2], dw[3]);
  } else {
    int F2 = (blk - 25) * 256 + tid;   // 0..1023
    int lane = F2 & 63, E = F2 >> 6;
    int nt = E >> 2, ks = E & 3;
    int n = lane & 15, quad = lane >> 4;
    int p = nt * 16 + n;
    unsigned dw[4];
    #pragma unroll
    for (int t2 = 0; t2 < 4; t2++) {
      int c = ks * 16 + quad * 4 + t2;
      dw[t2] = pkhf(c2pr[p * 64 + c], -c2pi[p * 64 + c]);
    }
    ((uint4*)((char*)ws + 197632))[E * 64 + lane] = make_uint4(dw[0], dw[1], dw[2], dw[3]);
  }
}

// ONE frame per block, 800 blocks. Phase A vectorized: thread t owns ADJACENT
// bins f=2t,2t+1; one unaligned dwordx4 per (channel, re/im) covers all six
// operands of both bins (window [2t-1 .. 2t+2]). Edge threads t=0,255 take
// the original scalar path. K-loop: 2-deep register prefetch of B-frags
// (L2-hot). LDS = vsh 16,384 B. [verified 108.1us structure — unchanged]
//   vsh uint[8][512] @0  (XOR-chunk swizzle (c,f): c*512+(((f>>2)^c)<<2)+(f&3))
//   epilogue: bcsh uint[48][68] overlays vsh
__global__ __launch_bounds__(256, 3) void pv_main(
    const float* __restrict__ br, const float* __restrict__ bi,
    const float* __restrict__ ws, float* __restrict__ out)
{
  __shared__ __align__(16) unsigned smem[4096];

  const int bt  = blockIdx.x;          // 0..799 = b*T + t
  const int tid = threadIdx.x;

  const int mt   = tid >> 6;       // wave id = M-tile
  const int lane = tid & 63;
  const int m16  = lane & 15;
  const int quad = lane >> 4;
  const int p    = mt * 16 + m16;
  const int ich  = p >> 3, jch = p & 7;
  const uint4* BF0 = (const uint4*)((const char*)ws + 1024);

  // ---- phase A: bins 2t,2t+1 per thread -> vsh (fp16 pairs, swizzled) ----
  {
    const float* pr  = br + (size_t)bt * (NCH_ * NBIN_);
    const float* pim = bi + (size_t)bt * (NCH_ * NBIN_);
    unsigned* vsh = smem;
    const int f0 = 2 * tid;
    if (tid == 0 || tid == 255) {
      // original scalar path for edge bins (exact reference index mapping)
      #pragma unroll
      for (int bb = 0; bb < 2; bb++) {
        const int f = f0 + bb;
        const int fm = (f == 0) ? 0 : ((f == 511) ? 509 : f - 1);
        const int fp = (f == 0) ? 2 : ((f == 511) ? 511 : f + 1);
        float tr = 0.f;
        float t1[8], t2[8];
        #pragma unroll
        for (int c = 0; c < 8; c++) {
          const float* cr = pr + c * 512;
          const float* ci = pim + c * 512;
          float xr = cr[f],   xi = ci[f];
          float xrm = cr[fm], xim = ci[fm];
          float xrp = cr[fp], xip = ci[fp];
          tr = fmaf(xr, xr, tr); tr = fmaf(xi, xi, tr);
          float Gr = fmaf(xrm, xrp,  xim * xip);
          float Gi = fmaf(xrm, xip, -(xim * xrp));
          float am = fmaxf(fmaxf(fabsf(Gr), fabsf(Gi)), 1e-30f);
          float rc = __builtin_amdgcn_rcpf(am);
          float q1 = Gr * rc, q2 = Gi * rc;
          float n2 = fmaf(q1, q1, q2 * q2);
          float rn = __builtin_amdgcn_rsqf(n2);
          bool ok = n2 > 0.f;
          float ur = ok ? q1 * rn : 1.f;
          float ui = ok ? q2 * rn : 0.f;
          float mg = __builtin_amdgcn_sqrtf(fmaf(xr, xr, xi * xi));
          t1[c] = mg * ur; t2[c] = mg * ui;
        }
        float scv = __builtin_amdgcn_rsqf(fmaxf(tr, 1e-20f));
        const int fc = f >> 2, fl = f & 3;
        #pragma unroll
        for (int c = 0; c < 8; c++)
          vsh[c * 512 + ((fc ^ c) << 2) + fl] = pkhf(t1[c] * scv, t2[c] * scv);
      }
    } else {
      const int base = f0 - 1;           // window [f0-1 .. f0+2], in-bounds
      float tra = 0.f, trb = 0.f;
      float t1a[8], t2a[8], t1b[8], t2b[8];
      #pragma unroll
      for (int c = 0; c < 8; c++) {
        float4 wr, wi;
        __builtin_memcpy(&wr, pr + c * 512 + base, 16);
        __builtin_memcpy(&wi, pim + c * 512 + base, 16);
        // bin0 = f0: xr=wr.y,xi=wi.y  fm=(wr.x,wi.x)  fp=(wr.z,wi.z)
        {
          float xr = wr.y, xi = wi.y;
          float xrm = wr.x, xim = wi.x;
          float xrp = wr.z, xip = wi.z;
          tra = fmaf(xr, xr, tra); tra = fmaf(xi, xi, tra);
          float Gr = fmaf(xrm, xrp,  xim * xip);
          float Gi = fmaf(xrm, xip, -(xim * xrp));
          float am = fmaxf(fmaxf(fabsf(Gr), fabsf(Gi)), 1e-30f);
          float rc = __builtin_amdgcn_rcpf(am);
          float q1 = Gr * rc, q2 = Gi * rc;
          float n2 = fmaf(q1, q1, q2 * q2);
          float rn = __builtin_amdgcn_rsqf(n2);
          bool ok = n2 > 0.f;
          float ur = ok ? q1 * rn : 1.f;
          float ui = ok ? q2 * rn : 0.f;
          float mg = __builtin_amdgcn_sqrtf(fmaf(xr, xr, xi * xi));
          t1a[c] = mg * ur; t2a[c] = mg * ui;
        }
        // bin1 = f0+1: xr=wr.z,xi=wi.z  fm=(wr.y,wi.y)  fp=(wr.w,wi.w)
        {
          float xr = wr.z, xi = wi.z;
          float xrm = wr.y, xim = wi.y;
          float xrp = wr.w, xip = wi.w;
          trb = fmaf(xr, xr, trb); trb = fmaf(xi, xi, trb);
          float Gr = fmaf(xrm, xrp,  xim * xip);
          float Gi = fmaf(xrm, xip, -(xim * xrp));
          float am = fmaxf(fmaxf(fabsf(Gr), fabsf(Gi)), 1e-30f);
          float rc = __builtin_amdgcn_rcpf(am);
          float q1 = Gr * rc, q2 = Gi * rc;
          float n2 = fmaf(q1, q1, q2 * q2);
          float rn = __builtin_amdgcn_rsqf(n2);
          bool ok = n2 > 0.f;
          float ur = ok ? q1 * rn : 1.f;
          float ui = ok ? q2 * rn : 0.f;
          float mg = __builtin_amdgcn_sqrtf(fmaf(xr, xr, xi * xi));
          t1b[c] = mg * ur; t2b[c] = mg * ui;
        }
      }
      float scva = __builtin_amdgcn_rsqf(fmaxf(tra, 1e-20f));
      float scvb = __builtin_amdgcn_rsqf(fmaxf(trb, 1e-20f));
      const int fc = f0 >> 2, fl = f0 & 3;   // fl in {0,2}; same chunk for both bins
      #pragma unroll
      for (int c = 0; c < 8; c++) {
        unsigned d0 = pkhf(t1a[c] * scva, t2a[c] * scva);
        unsigned d1 = pkhf(t1b[c] * scvb, t2b[c] * scvb);
        *(uint2*)(vsh + c * 512 + ((fc ^ c) << 2) + fl) = make_uint2(d0, d1);
      }
    }
  }
  __syncthreads();               // vsh ready; K-loop below is barrier-free

  // ---- band GEMM: 32 K-steps; B-frags from L2 via 2-deep reg prefetch ----
  float4v acc[6];                // [0..2]=real cols, [3..5]=imag cols
  #pragma unroll
  for (int g = 0; g < 6; g++) acc[g] = (float4v){0.f, 0.f, 0.f, 0.f};

  const uint4* Bg = BF0 + lane;
  uint4 pa0 = Bg[0],   pa1 = Bg[64],  pa2 = Bg[128];   // step s
  uint4 pb0 = Bg[192], pb1 = Bg[256], pb2 = Bg[320];   // step s+1
  #pragma unroll 4
  for (int s = 0; s < 32; s++) {
    uint4 cb0 = pa0, cb1 = pa1, cb2 = pa2;
    pa0 = pb0; pa1 = pb1; pa2 = pb2;
    {
      const uint4* nx = Bg + (size_t)(((s + 2) & 31) * 192);
      pb0 = nx[0]; pb1 = nx[64]; pb2 = nx[128];
    }
    const int sc = s * 4 + quad;           // chunk index pre-swizzle
    half8 b0 = __builtin_bit_cast(half8, cb0);
    half8 b1 = __builtin_bit_cast(half8, cb1);
    half8 b2 = __builtin_bit_cast(half8, cb2);
    const uint4* vb = (const uint4*)smem;
    uint4 av = vb[ich * 128 + (sc ^ ich)];
    uint4 bv = vb[jch * 128 + (sc ^ jch)];
    unsigned a0 = cmulc(av.x, bv.x);
    unsigned a1 = cmulc(av.y, bv.y);
    unsigned a2 = cmulc(av.z, bv.z);
    unsigned a3 = cmulc(av.w, bv.w);
    uint4 au1 = make_uint4(a0 ^ 0x80000000u, a1 ^ 0x80000000u,
                           a2 ^ 0x80000000u, a3 ^ 0x80000000u); // (ar, -ai)
    uint4 au2 = make_uint4(rot16(a0), rot16(a1),
                           rot16(a2), rot16(a3));               // (ai, ar)
    half8 af1 = __builtin_bit_cast(half8, au1);
    half8 af2 = __builtin_bit_cast(half8, au2);
    acc[0] = __builtin_amdgcn_mfma_f32_16x16x32_f16(af1, b0, acc[0], 0, 0, 0);
    acc[3] = __builtin_amdgcn_mfma_f32_16x16x32_f16(af2, b0, acc[3], 0, 0, 0);
    acc[1] = __builtin_amdgcn_mfma_f32_16x16x32_f16(af1, b1, acc[1], 0, 0, 0);
    acc[4] = __builtin_amdgcn_mfma_f32_16x16x32_f16(af2, b1, acc[4], 0, 0, 0);
    acc[2] = __builtin_amdgcn_mfma_f32_16x16x32_f16(af1, b2, acc[2], 0, 0, 0);
    acc[5] = __builtin_amdgcn_mfma_f32_16x16x32_f16(af2, b2, acc[5], 0, 0, 0);
  }
  __syncthreads();               // all waves done reading vsh before overlay

  // ---- epilogue GEMM: pv[k][p] = Re(sum_c c2p[p][c]*bc[k][c]) ----
  const uint4* EF = ((const uint4*)((const char*)ws + 197632)) + (mt * 4) * 64 + lane;
  uint4 eb[4];
  #pragma unroll
  for (int ks = 0; ks < 4; ks++) eb[ks] = EF[ks * 64];

  {
    unsigned* bcsh = smem;             // [48][68] fp16-pair, overlays vsh
    #pragma unroll
    for (int n = 0; n < 3; n++) {
      uint4 w4 = make_uint4(pkhf(acc[n][0], acc[n+3][0]),
                            pkhf(acc[n][1], acc[n+3][1]),
                            pkhf(acc[n][2], acc[n+3][2]),
                            pkhf(acc[n][3], acc[n+3][3]));
      *(uint4*)(bcsh + (n * 16 + m16) * 68 + mt * 16 + quad * 4) = w4;
    }
  }
  __syncthreads();

  const float4* wsd = (const float4*)ws;   // dsinv[40]
  {
    const unsigned* bcsh = smem;
    float4v eacc[3];
    #pragma unroll
    for (int kt = 0; kt < 3; kt++) eacc[kt] = (float4v){0.f, 0.f, 0.f, 0.f};
    #pragma unroll
    for (int ks = 0; ks < 4; ks++) {
      half8 bfr = __builtin_bit_cast(half8, eb[ks]);
      #pragma unroll
      for (int kt = 0; kt < 3; kt++) {
        uint4 a4 = *(const uint4*)(bcsh + (kt * 16 + m16) * 68 + ks * 16 + quad * 4);
        half8 afr = __builtin_bit_cast(half8, a4);
        eacc[kt] = __builtin_amdgcn_mfma_f32_16x16x32_f16(afr, bfr, eacc[kt], 0, 0, 0);
      }
    }
    float* op = out + (size_t)bt * (NBAND_ * NPV_);
    #pragma unroll
    for (int kt = 0; kt < 3; kt++) {
      float4 dv = wsd[kt * 4 + quad];
      float dva[4] = {dv.x, dv.y, dv.z, dv.w};
      #pragma unroll
      for (int r = 0; r < 4; r++) {
        int k = kt * 16 + quad * 4 + r;
        if (k < NBAND_)
          op[k * 64 + mt * 16 + m16] = eacc[kt][r] * dva[r];
      }
    }
  }
}

// ---------------- IIR: chunked scan, chunk=25, 160 blocks x 512 thr ----------------
// block = (b, k, ph); ph in {0,1} selects p-half [ph*32, ph*32+32).
// thread = (chunk c in [0,16), pl in [0,32)). A wave covers 32 consecutive p
// of chunks c and c+1 -> each load/store is two contiguous 128-B segments
// (still fully coalesced). vs round-11's 80-block version: CU coverage
// doubles 80 -> 160 (zero tail), per-block work halves. Same verified scan
// math with A = a^25; combine fold 15-deep. gsh[16][32].
__global__ __launch_bounds__(512) void pv_iir4(float* __restrict__ z,
                                               const float* __restrict__ tau)
{
  __shared__ float gsh[16][32];
  const int ph = blockIdx.x & 1;
  const int bk = blockIdx.x >> 1;            // 0..79 = b*40+k
  const int k = bk % NBAND_;
  const int b = bk / NBAND_;
  const float a  = tau[k];
  const float om = 1.0f - a;
  const int c  = threadIdx.x >> 5;           // chunk 0..15
  const int pl = threadIdx.x & 31;
  const int p  = ph * 32 + pl;
  const size_t stride = (size_t)NBAND_ * 64;
  size_t idx0 = (size_t)b * (T_ * NBAND_ * 64) + (size_t)(c * 25) * stride + k * 64 + p;

  float y[25];
  float accv = 0.f;
  #pragma unroll
  for (int i = 0; i < 25; i++) {
    float v = z[idx0 + (size_t)i * stride];
    accv = fmaf(a, accv, om * v);
    y[i] = accv;
  }
  gsh[c][pl] = accv;
  __syncthreads();
  float a2 = a * a, a4 = a2 * a2, a8 = a4 * a4, a16 = a8 * a8;
  float A = a16 * a8 * a;                    // a^25
  float H = 0.f;
  #pragma unroll
  for (int d = 0; d < 15; d++) {
    float g = gsh[d][pl];
    H = (d < c) ? fmaf(A, H, g) : H;
  }
  float wp = a;
  #pragma unroll
  for (int i = 0; i < 25; i++) {
    z[idx0 + (size_t)i * stride] = fmaf(wp, H, y[i]);
    wp *= a;
  }
}

extern "C" void kernel_launch(void* const* d_in, const int* in_sizes, int n_in,
                              void* d_out, int out_size, void* d_ws, size_t ws_size,
                              hipStream_t stream)
{
  const float* br   = (const float*)d_in[0];
  const float* bi   = (const float*)d_in[1];
  const float* bmr  = (const float*)d_in[2];
  const float* bmi  = (const float*)d_in[3];
  const float* c2pr = (const float*)d_in[4];
  const float* c2pi = (const float*)d_in[5];
  const float* tau  = (const float*)d_in[6];
  float* out = (float*)d_out;
  float* ws  = (float*)d_ws;

  hipLaunchKernelGGL(pv_prep, dim3(29), dim3(256), 0, stream,
                     bmr, bmi, c2pr, c2pi, ws);
  hipLaunchKernelGGL(pv_main, dim3(B_ * T_), dim3(256), 0, stream,
                     br, bi, ws, out);
  hipLaunchKernelGGL(pv_iir4, dim3(B_ * NBAND_ * 2), dim3(512), 0, stream,
                     out, tau);
}

// Round 13
// 107.774 us; speedup vs baseline: 1.1551x; 1.0009x over previous
//
#include <hip/hip_runtime.h>
#include <hip/hip_fp16.h>

#define B_    2
#define T_    400
#define NCH_  8
#define NBIN_ 512
#define NBAND_ 40
#define NPV_  64

using half8   = __attribute__((ext_vector_type(8))) _Float16;
using float4v = __attribute__((ext_vector_type(4))) float;

// pack two floats into fp16 pair dword (lo=x, hi=y), RNE
static __device__ inline unsigned pkhf(float x, float y) {
  __half2 h = __float22half2_rn(make_float2(x, y));
  return __builtin_bit_cast(unsigned, h);
}
static __device__ inline unsigned rot16(unsigned u) {
  return (u >> 16) | (u << 16);
}
// packed complex multiply a = v_i * conj(v_j); dwords are (lo=re, hi=im)
static __device__ inline unsigned cmulc(unsigned viu, unsigned vju) {
  __half2 Vi = __builtin_bit_cast(__half2, viu);
  __half2 Vj = __builtin_bit_cast(__half2, vju);
  __half2 P1 = __hmul2(Vi, __low2half2(Vj));
  __half2 Qi = __lowhigh2highlow(Vi);
  unsigned tn = __builtin_bit_cast(unsigned, __high2half2(Vj)) ^ 0x80000000u;
  __half2 a  = __hfma2(Qi, __builtin_bit_cast(__half2, tn), P1);
  return __builtin_bit_cast(unsigned, a);
}

// ws layout (bytes):
//   [0..159]              : dsinv[40] floats
//   [1024, 1024+98304)    : band B-frags (fp16 pairs), s-major, stored once:
//                           F=(s*3+n)*64+lane, uint4; dword t = (bmr, bmi) at
//                           f = s*16 + (lane>>4)*4 + t, k = n*16 + (lane&15)
//   [197632, 197632+16384): epi B-frags (fp16): E=(nt*4+ks)*64+lane, uint4
__global__ __launch_bounds__(256) void pv_prep(
    const float* __restrict__ bmr, const float* __restrict__ bmi,
    const float* __restrict__ c2pr, const float* __restrict__ c2pi,
    float* __restrict__ ws)
{
  const int tid = threadIdx.x;
  const int blk = blockIdx.x;
  if (blk == 0) {
    __shared__ float sds[256];
    int k = tid & 63, part = tid >> 6;
    float s = 0.f;
    if (k < NBAND_) {
      const float* col = bmr + k;
      #pragma unroll 16
      for (int f = part * 128; f < part * 128 + 128; f++) s += col[f * 40];
    }
    sds[tid] = s;
    __syncthreads();
    if (tid < NBAND_) {
      float t = sds[tid] + sds[tid + 64] + sds[tid + 128] + sds[tid + 192];
      ws[tid] = 1.0f / fmaxf(t, 1e-20f);
    }
  } else if (blk <= 24) {
    int F = (blk - 1) * 256 + tid;     // 0..6143
    int l = F & 63;
    int fid = F >> 6;                  // s*3 + n
    int s5 = fid / 3;
    int n = fid - s5 * 3;
    int k = n * 16 + (l & 15);
    int quad = l >> 4;
    unsigned dw[4];
    #pragma unroll
    for (int t2 = 0; t2 < 4; t2++) {
      float v0 = 0.f, v1 = 0.f;
      if (k < NBAND_) {
        int f = s5 * 16 + quad * 4 + t2;
        v0 = bmr[f * 40 + k]; v1 = bmi[f * 40 + k];
      }
      dw[t2] = pkhf(v0, v1);
    }
    ((uint4*)((char*)ws + 1024))[F] = make_uint4(dw[0], dw[1], dw[2], dw[3]);
  } else {
    int F2 = (blk - 25) * 256 + tid;   // 0..1023
    int lane = F2 & 63, E = F2 >> 6;
    int nt = E >> 2, ks = E & 3;
    int n = lane & 15, quad = lane >> 4;
    int p = nt * 16 + n;
    unsigned dw[4];
    #pragma unroll
    for (int t2 = 0; t2 < 4; t2++) {
      int c = ks * 16 + quad * 4 + t2;
      dw[t2] = pkhf(c2pr[p * 64 + c], -c2pi[p * 64 + c]);
    }
    ((uint4*)((char*)ws + 197632))[E * 64 + lane] = make_uint4(dw[0], dw[1], dw[2], dw[3]);
  }
}

// ONE frame per block, 800 blocks. Phase A is now TWO-PASS through LDS:
//   pass 1: stage the whole 32 KB frame (re+im) with ALIGNED, fully-coalesced
//           float4 loads (frame base is 16 KB-aligned; 8 float4/thread/array)
//           -- replaces the 16-B-MISALIGNED per-thread window loads that every
//           prior variant kept (suspected split/scalar lowering).
//   pass 2: verbatim round-2 reference math (f = fs*256+tid, clamped fm/fp)
//           reading from LDS (4-B access free) -- edge special-case gone.
// K-loop: 2-deep register prefetch of B-frags (L2-hot), unchanged.
// LDS 48 KB: raw_re[8][512]f32 @0, raw_im @4096dw, vsh @8192dw -> 3 blocks/CU.
//   vsh uint[8][512] (XOR-chunk swizzle (c,f): c*512+(((f>>2)^c)<<2)+(f&3))
//   epilogue: bcsh uint[48][68] overlays raw_re (dead after pass 2)
__global__ __launch_bounds__(256, 3) void pv_main(
    const float* __restrict__ br, const float* __restrict__ bi,
    const float* __restrict__ ws, float* __restrict__ out)
{
  __shared__ __align__(16) unsigned smem[12288];

  const int bt  = blockIdx.x;          // 0..799 = b*T + t
  const int tid = threadIdx.x;

  const int mt   = tid >> 6;       // wave id = M-tile
  const int lane = tid & 63;
  const int m16  = lane & 15;
  const int quad = lane >> 4;
  const int p    = mt * 16 + m16;
  const int ich  = p >> 3, jch = p & 7;
  const uint4* BF0 = (const uint4*)((const char*)ws + 1024);
  unsigned* vsh = smem + 8192;

  // ---- phase A pass 1: stage frame into LDS (aligned, coalesced) ----
  {
    const float4* gr4 = (const float4*)(br + (size_t)bt * (NCH_ * NBIN_));
    const float4* gi4 = (const float4*)(bi + (size_t)bt * (NCH_ * NBIN_));
    float4* lr4 = (float4*)smem;             // raw_re[8][512] as float4[1024]
    float4* li4 = (float4*)(smem + 4096);    // raw_im
    #pragma unroll
    for (int it = 0; it < 4; it++) {
      lr4[it * 256 + tid] = gr4[it * 256 + tid];
      li4[it * 256 + tid] = gi4[it * 256 + tid];
    }
  }
  __syncthreads();

  // ---- phase A pass 2: verbatim reference math, inputs from LDS ----
  {
    const float* rr = (const float*)smem;           // raw_re[c*512 + f]
    const float* ri = (const float*)(smem + 4096);  // raw_im
    #pragma unroll
    for (int fs = 0; fs < 2; fs++) {
      const int f = fs * 256 + tid;
      const int fm = (f == 0) ? 0 : ((f == 511) ? 509 : f - 1);
      const int fp = (f == 0) ? 2 : ((f == 511) ? 511 : f + 1);
      float tr = 0.f;
      float t1[8], t2[8];
      #pragma unroll
      for (int c = 0; c < 8; c++) {
        const float* cr = rr + c * 512;
        const float* ci = ri + c * 512;
        float xr = cr[f],   xi = ci[f];
        float xrm = cr[fm], xim = ci[fm];
        float xrp = cr[fp], xip = ci[fp];
        tr = fmaf(xr, xr, tr); tr = fmaf(xi, xi, tr);
        float Gr = fmaf(xrm, xrp,  xim * xip);
        float Gi = fmaf(xrm, xip, -(xim * xrp));
        float am = fmaxf(fmaxf(fabsf(Gr), fabsf(Gi)), 1e-30f);
        float rc = __builtin_amdgcn_rcpf(am);
        float q1 = Gr * rc, q2 = Gi * rc;
        float n2 = fmaf(q1, q1, q2 * q2);
        float rn = __builtin_amdgcn_rsqf(n2);
        bool ok = n2 > 0.f;
        float ur = ok ? q1 * rn : 1.f;
        float ui = ok ? q2 * rn : 0.f;
        float mg = __builtin_amdgcn_sqrtf(fmaf(xr, xr, xi * xi));
        t1[c] = mg * ur; t2[c] = mg * ui;
      }
      float scv = __builtin_amdgcn_rsqf(fmaxf(tr, 1e-20f));
      const int fc = f >> 2, fl = f & 3;
      #pragma unroll
      for (int c = 0; c < 8; c++)
        vsh[c * 512 + ((fc ^ c) << 2) + fl] = pkhf(t1[c] * scv, t2[c] * scv);
    }
  }
  __syncthreads();               // vsh ready; K-loop below is barrier-free

  // ---- band GEMM: 32 K-steps; B-frags from L2 via 2-deep reg prefetch ----
  float4v acc[6];                // [0..2]=real cols, [3..5]=imag cols
  #pragma unroll
  for (int g = 0; g < 6; g++) acc[g] = (float4v){0.f, 0.f, 0.f, 0.f};

  const uint4* Bg = BF0 + lane;
  uint4 pa0 = Bg[0],   pa1 = Bg[64],  pa2 = Bg[128];   // step s
  uint4 pb0 = Bg[192], pb1 = Bg[256], pb2 = Bg[320];   // step s+1
  #pragma unroll 4
  for (int s = 0; s < 32; s++) {
    uint4 cb0 = pa0, cb1 = pa1, cb2 = pa2;
    pa0 = pb0; pa1 = pb1; pa2 = pb2;
    {
      const uint4* nx = Bg + (size_t)(((s + 2) & 31) * 192);
      pb0 = nx[0]; pb1 = nx[64]; pb2 = nx[128];
    }
    const int sc = s * 4 + quad;           // chunk index pre-swizzle
    half8 b0 = __builtin_bit_cast(half8, cb0);
    half8 b1 = __builtin_bit_cast(half8, cb1);
    half8 b2 = __builtin_bit_cast(half8, cb2);
    const uint4* vb = (const uint4*)vsh;
    uint4 av = vb[ich * 128 + (sc ^ ich)];
    uint4 bv = vb[jch * 128 + (sc ^ jch)];
    unsigned a0 = cmulc(av.x, bv.x);
    unsigned a1 = cmulc(av.y, bv.y);
    unsigned a2 = cmulc(av.z, bv.z);
    unsigned a3 = cmulc(av.w, bv.w);
    uint4 au1 = make_uint4(a0 ^ 0x80000000u, a1 ^ 0x80000000u,
                           a2 ^ 0x80000000u, a3 ^ 0x80000000u); // (ar, -ai)
    uint4 au2 = make_uint4(rot16(a0), rot16(a1),
                           rot16(a2), rot16(a3));               // (ai, ar)
    half8 af1 = __builtin_bit_cast(half8, au1);
    half8 af2 = __builtin_bit_cast(half8, au2);
    acc[0] = __builtin_amdgcn_mfma_f32_16x16x32_f16(af1, b0, acc[0], 0, 0, 0);
    acc[3] = __builtin_amdgcn_mfma_f32_16x16x32_f16(af2, b0, acc[3], 0, 0, 0);
    acc[1] = __builtin_amdgcn_mfma_f32_16x16x32_f16(af1, b1, acc[1], 0, 0, 0);
    acc[4] = __builtin_amdgcn_mfma_f32_16x16x32_f16(af2, b1, acc[4], 0, 0, 0);
    acc[2] = __builtin_amdgcn_mfma_f32_16x16x32_f16(af1, b2, acc[2], 0, 0, 0);
    acc[5] = __builtin_amdgcn_mfma_f32_16x16x32_f16(af2, b2, acc[5], 0, 0, 0);
  }
  __syncthreads();               // all waves done with K-loop

  // ---- epilogue GEMM: pv[k][p] = Re(sum_c c2p[p][c]*bc[k][c]) ----
  const uint4* EF = ((const uint4*)((const char*)ws + 197632)) + (mt * 4) * 64 + lane;
  uint4 eb[4];
  #pragma unroll
  for (int ks = 0; ks < 4; ks++) eb[ks] = EF[ks * 64];

  {
    unsigned* bcsh = smem;             // [48][68] fp16-pair, overlays raw_re
    #pragma unroll
    for (int n = 0; n < 3; n++) {
      uint4 w4 = make_uint4(pkhf(acc[n][0], acc[n+3][0]),
                            pkhf(acc[n][1], acc[n+3][1]),
                            pkhf(acc[n][2], acc[n+3][2]),
                            pkhf(acc[n][3], acc[n+3][3]));
      *(uint4*)(bcsh + (n * 16 + m16) * 68 + mt * 16 + quad * 4) = w4;
    }
  }
  __syncthreads();

  const float4* wsd = (const float4*)ws;   // dsinv[40]
  {
    const unsigned* bcsh = smem;
    float4v eacc[3];
    #pragma unroll
    for (int kt = 0; kt < 3; kt++) eacc[kt] = (float4v){0.f, 0.f, 0.f, 0.f};
    #pragma unroll
    for (int ks = 0; ks < 4; ks++) {
      half8 bfr = __builtin_bit_cast(half8, eb[ks]);
      #pragma unroll
      for (int kt = 0; kt < 3; kt++) {
        uint4 a4 = *(const uint4*)(bcsh + (kt * 16 + m16) * 68 + ks * 16 + quad * 4);
        half8 afr = __builtin_bit_cast(half8, a4);
        eacc[kt] = __builtin_amdgcn_mfma_f32_16x16x32_f16(afr, bfr, eacc[kt], 0, 0, 0);
      }
    }
    float* op = out + (size_t)bt * (NBAND_ * NPV_);
    #pragma unroll
    for (int kt = 0; kt < 3; kt++) {
      float4 dv = wsd[kt * 4 + quad];
      float dva[4] = {dv.x, dv.y, dv.z, dv.w};
      #pragma unroll
      for (int r = 0; r < 4; r++) {
        int k = kt * 16 + quad * 4 + r;
        if (k < NBAND_)
          op[k * 64 + mt * 16 + m16] = eacc[kt][r] * dva[r];
      }
    }
  }
}

// ---------------- IIR: chunked scan, chunk=25, 160 blocks x 512 thr ----------------
// block = (b, k, ph); ph in {0,1} selects p-half [ph*32, ph*32+32).
// thread = (chunk c in [0,16), pl in [0,32)). A wave covers 32 consecutive p
// of chunks c and c+1 -> each load/store is two contiguous 128-B segments
// (fully coalesced). Same verified scan math with A = a^25. gsh[16][32].
__global__ __launch_bounds__(512) void pv_iir4(float* __restrict__ z,
                                               const float* __restrict__ tau)
{
  __shared__ float gsh[16][32];
  const int ph = blockIdx.x & 1;
  const int bk = blockIdx.x >> 1;            // 0..79 = b*40+k
  const int k = bk % NBAND_;
  const int b = bk / NBAND_;
  const float a  = tau[k];
  const float om = 1.0f - a;
  const int c  = threadIdx.x >> 5;           // chunk 0..15
  const int pl = threadIdx.x & 31;
  const int p  = ph * 32 + pl;
  const size_t stride = (size_t)NBAND_ * 64;
  size_t idx0 = (size_t)b * (T_ * NBAND_ * 64) + (size_t)(c * 25) * stride + k * 64 + p;

  float y[25];
  float accv = 0.f;
  #pragma unroll
  for (int i = 0; i < 25; i++) {
    float v = z[idx0 + (size_t)i * stride];
    accv = fmaf(a, accv, om * v);
    y[i] = accv;
  }
  gsh[c][pl] = accv;
  __syncthreads();
  float a2 = a * a, a4 = a2 * a2, a8 = a4 * a4, a16 = a8 * a8;
  float A = a16 * a8 * a;                    // a^25
  float H = 0.f;
  #pragma unroll
  for (int d = 0; d < 15; d++) {
    float g = gsh[d][pl];
    H = (d < c) ? fmaf(A, H, g) : H;
  }
  float wp = a;
  #pragma unroll
  for (int i = 0; i < 25; i++) {
    z[idx0 + (size_t)i * stride] = fmaf(wp, H, y[i]);
    wp *= a;
  }
}

extern "C" void kernel_launch(void* const* d_in, const int* in_sizes, int n_in,
                              void* d_out, int out_size, void* d_ws, size_t ws_size,
                              hipStream_t stream)
{
  const float* br   = (const float*)d_in[0];
  const float* bi   = (const float*)d_in[1];
  const float* bmr  = (const float*)d_in[2];
  const float* bmi  = (const float*)d_in[3];
  const float* c2pr = (const float*)d_in[4];
  const float* c2pi = (const float*)d_in[5];
  const float* tau  = (const float*)d_in[6];
  float* out = (float*)d_out;
  float* ws  = (float*)d_ws;

  hipLaunchKernelGGL(pv_prep, dim3(29), dim3(256), 0, stream,
                     bmr, bmi, c2pr, c2pi, ws);
  hipLaunchKernelGGL(pv_main, dim3(B_ * T_), dim3(256), 0, stream,
                     br, bi, ws, out);
  hipLaunchKernelGGL(pv_iir4, dim3(B_ * NBAND_ * 2), dim3(512), 0, stream,
                     out, tau);
}